// Round 6
// baseline (138.303 us; speedup 1.0000x reference)
//
#include <hip/hip_runtime.h>

typedef float f32x4 __attribute__((ext_vector_type(4)));

// Problem constants
constexpr int B = 1024;
constexpr int C = 1024;
constexpr int K = 20;
constexpr int L = 2048;
constexpr int V = 80;
constexpr int TK = 3 * K;  // 60

// Output layout: w [B,V] @0 ; kappa [B,K] @B*V ; phi [B,L+1] @B*V+B*K
constexpr size_t OUT_KAPPA = (size_t)B * V;
constexpr size_t OUT_PHI   = OUT_KAPPA + (size_t)B * K;

// R6 single-variable A/B vs R5: plain cached loads instead of nontemporal.
#define NTLOAD(p) (*(p))

__global__ __launch_bounds__(256, 4)
void window_fused_kernel(const float* __restrict__ x,
                         const float* __restrict__ W,
                         const float* __restrict__ bias,
                         const float* __restrict__ kappa_old,
                         const float* __restrict__ onehots,
                         const int*   __restrict__ text_lens,
                         float* __restrict__ out) {
    const int b = blockIdx.x;
    const int t = threadIdx.x;

    __shared__ float lds_x[C];           // 4 KB
    __shared__ float lds_phi[L];         // 8 KB
    __shared__ float lds_abk[TK];        // alpha/beta/kappa
    __shared__ float lds_part[4][TK];    // GEMM cross-wave partials
    __shared__ float lds_w[V];

    const f32x4* oh = reinterpret_cast<const f32x4*>(onehots + (size_t)b * L * V);

    // ---- Early prefetch: quads A,B,C in flight across the whole prefix ----
    f32x4 A0 = NTLOAD(oh + t);         f32x4 A1 = NTLOAD(oh + t + 256);
    f32x4 A2 = NTLOAD(oh + t + 512);   f32x4 A3 = NTLOAD(oh + t + 768);
    f32x4 B0 = NTLOAD(oh + t + 1024);  f32x4 B1 = NTLOAD(oh + t + 1280);
    f32x4 B2 = NTLOAD(oh + t + 1536);  f32x4 B3 = NTLOAD(oh + t + 1792);
    f32x4 C0 = NTLOAD(oh + t + 2048);  f32x4 C1 = NTLOAD(oh + t + 2304);
    f32x4 C2 = NTLOAD(oh + t + 2560);  f32x4 C3 = NTLOAD(oh + t + 2816);

    // ---- stage x[b,:] ----
    reinterpret_cast<float4*>(lds_x)[t] =
        reinterpret_cast<const float4*>(x + (size_t)b * C)[t];
    if (t < V) lds_w[t] = 0.0f;
    __syncthreads();

    // ---- GEMM: wave sub covers 256 rows of C; lane g owns column g ----
    {
        const int sub = t >> 6;
        const int g   = t & 63;
        if (g < TK) {
            const int c0 = sub * 256;
            const float* pW = W + (size_t)c0 * TK + g;
            float acc = 0.0f;
            #pragma unroll 16
            for (int i = 0; i < 256; ++i)
                acc += lds_x[c0 + i] * pW[(size_t)i * TK];
            lds_part[sub][g] = acc;
        }
    }
    __syncthreads();
    if (t < TK) {
        const float dot = lds_part[0][t] + lds_part[1][t]
                        + lds_part[2][t] + lds_part[3][t];
        const float p = __expf(dot + bias[t]);
        float v = p;
        if (t >= 2 * K) {
            const int k = t - 2 * K;
            v = kappa_old[(size_t)b * K + k] + p;
            out[OUT_KAPPA + (size_t)b * K + k] = v;
        }
        lds_abk[t] = v;
    }
    __syncthreads();

    // ---- 4th prefetch quad between GEMM and phi ----
    f32x4 D0 = NTLOAD(oh + t + 3072);  f32x4 D1 = NTLOAD(oh + t + 3328);
    f32x4 D2 = NTLOAD(oh + t + 3584);  f32x4 D3 = NTLOAD(oh + t + 3840);

    // ---- phi[l] = scale * sum_k alpha_k * exp(-beta_k*(kappa_k-l)^2) ----
    {
        float s[8];
        #pragma unroll
        for (int j = 0; j < 8; ++j) s[j] = 0.0f;
        #pragma unroll
        for (int k = 0; k < K; ++k) {
            const float a  = lds_abk[k];
            const float be = lds_abk[K + k];
            const float kp = lds_abk[2 * K + k];
            #pragma unroll
            for (int j = 0; j < 8; ++j) {
                const float d = kp - (float)(t + (j << 8));
                s[j] += a * __expf(-be * d * d);
            }
        }
        const float scale = 2048.0f / (float)text_lens[b];
        float* out_phi = out + OUT_PHI + (size_t)b * (L + 1);
        #pragma unroll
        for (int j = 0; j < 8; ++j) {
            const int l = t + (j << 8);
            const float v = s[j] * scale;
            lds_phi[l] = v;
            out_phi[l] = v;
        }
        if (t == 0) {  // tail l = 2048 (output only)
            float sv = 0.0f;
            #pragma unroll
            for (int k = 0; k < K; ++k) {
                const float d = lds_abk[2 * K + k] - 2048.0f;
                sv += lds_abk[k] * __expf(-lds_abk[K + k] * d * d);
            }
            out_phi[L] = sv * scale;
        }
    }
    __syncthreads();

    // ---- stream: w[v] += phi[l] * onehots[b,l,v]; 16-deep pipeline ----
    {
        // one-hot rows: each 16B chunk holds at most one element, exactly 1.0f
        #define PROC(vv, ii) {                                          \
            const float s_ = vv.x + vv.y + vv.z + vv.w;                 \
            if (s_ != 0.0f) {                                           \
                const int i_ = (ii);                                    \
                const int l_ = i_ / 20;                                 \
                const int v0 = (i_ - l_ * 20) * 4;                      \
                const int jo = (int)(vv.y + 2.0f * vv.z + 3.0f * vv.w); \
                atomicAdd(&lds_w[v0 + jo], lds_phi[l_]);                \
            } }
        #define REFILL(Q, base) {                                       \
            Q##0 = NTLOAD(oh + (base));       Q##1 = NTLOAD(oh + (base) + 256); \
            Q##2 = NTLOAD(oh + (base) + 512); Q##3 = NTLOAD(oh + (base) + 768); }

        // 160 chunks/thread = 40 quads; A/B/C/D rotating, 12-16 loads in flight
        #pragma unroll 1
        for (int q = 0; q < 40; q += 4) {
            const int ia = t + (q << 10);
            PROC(A0, ia);       PROC(A1, ia + 256);
            PROC(A2, ia + 512); PROC(A3, ia + 768);
            if (q + 4 < 40) REFILL(A, t + ((q + 4) << 10));
            const int ib = ia + 1024;
            PROC(B0, ib);       PROC(B1, ib + 256);
            PROC(B2, ib + 512); PROC(B3, ib + 768);
            if (q + 5 < 40) REFILL(B, t + ((q + 5) << 10));
            const int ic = ia + 2048;
            PROC(C0, ic);       PROC(C1, ic + 256);
            PROC(C2, ic + 512); PROC(C3, ic + 768);
            if (q + 6 < 40) REFILL(C, t + ((q + 6) << 10));
            const int id = ia + 3072;
            PROC(D0, id);       PROC(D1, id + 256);
            PROC(D2, id + 512); PROC(D3, id + 768);
            if (q + 7 < 40) REFILL(D, t + ((q + 7) << 10));
        }
        #undef REFILL
        #undef PROC
    }
    __syncthreads();

    if (t < V) out[(size_t)b * V + t] = lds_w[t];
}

extern "C" void kernel_launch(void* const* d_in, const int* in_sizes, int n_in,
                              void* d_out, int out_size, void* d_ws, size_t ws_size,
                              hipStream_t stream) {
    const float* x         = (const float*)d_in[0];
    const float* W         = (const float*)d_in[1];
    const float* bias      = (const float*)d_in[2];
    const float* kappa_old = (const float*)d_in[3];
    const float* onehots   = (const float*)d_in[4];
    const int*   text_lens = (const int*)d_in[5];
    float* out = (float*)d_out;

    window_fused_kernel<<<B, 256, 0, stream>>>(x, W, bias, kappa_old,
                                               onehots, text_lens, out);
}

// Round 7
// 129.010 us; speedup vs baseline: 1.0720x; 1.0720x over previous
//
#include <hip/hip_runtime.h>

typedef float f32x4 __attribute__((ext_vector_type(4)));

// Problem constants
constexpr int B = 1024;
constexpr int C = 1024;
constexpr int K = 20;
constexpr int L = 2048;
constexpr int V = 80;
constexpr int TK = 3 * K;  // 60

// Output layout: w [B,V] @0 ; kappa [B,K] @B*V ; phi [B,L+1] @B*V+B*K
constexpr size_t OUT_KAPPA = (size_t)B * V;
constexpr size_t OUT_PHI   = OUT_KAPPA + (size_t)B * K;

#define NTLOAD(p) __builtin_nontemporal_load(p)

// 2 rows per block: rows 2*bid and 2*bid+1 are contiguous in onehots, so each
// block streams one sequential 1.28 MB region; refills cross the row boundary
// so row 1's GEMM/phi prefix is hidden under in-flight row-1 loads.
__global__ __launch_bounds__(256, 2)
void window_fused_kernel(const float* __restrict__ x,
                         const float* __restrict__ W,
                         const float* __restrict__ bias,
                         const float* __restrict__ kappa_old,
                         const float* __restrict__ onehots,
                         const int*   __restrict__ text_lens,
                         float* __restrict__ out) {
    const int bid = blockIdx.x;
    const int t   = threadIdx.x;

    __shared__ float lds_x[C];           // 4 KB
    __shared__ float lds_phi[L];         // 8 KB
    __shared__ float lds_abk[TK];        // alpha/beta/kappa
    __shared__ float lds_part[4][TK];    // GEMM cross-wave partials
    __shared__ float lds_w[V];

    const f32x4* oh = reinterpret_cast<const f32x4*>(onehots + (size_t)(2 * bid) * L * V);

    // ---- Early prefetch: quads 0..2 of row 0 ----
    f32x4 A0 = NTLOAD(oh + t);         f32x4 A1 = NTLOAD(oh + t + 256);
    f32x4 A2 = NTLOAD(oh + t + 512);   f32x4 A3 = NTLOAD(oh + t + 768);
    f32x4 B0 = NTLOAD(oh + t + 1024);  f32x4 B1 = NTLOAD(oh + t + 1280);
    f32x4 B2 = NTLOAD(oh + t + 1536);  f32x4 B3 = NTLOAD(oh + t + 1792);
    f32x4 C0 = NTLOAD(oh + t + 2048);  f32x4 C1 = NTLOAD(oh + t + 2304);
    f32x4 C2 = NTLOAD(oh + t + 2560);  f32x4 C3 = NTLOAD(oh + t + 2816);
    f32x4 D0, D1, D2, D3;

    #pragma unroll 1
    for (int r = 0; r < 2; ++r) {
        const int b = 2 * bid + r;

        // ---- stage x[b,:]; zero w accumulator for this row ----
        reinterpret_cast<float4*>(lds_x)[t] =
            reinterpret_cast<const float4*>(x + (size_t)b * C)[t];
        if (t < V) lds_w[t] = 0.0f;
        __syncthreads();

        // ---- GEMM: wave sub covers 256 rows of C; lane g owns column g ----
        {
            const int sub = t >> 6;
            const int g   = t & 63;
            if (g < TK) {
                const int c0 = sub * 256;
                const float* pW = W + (size_t)c0 * TK + g;
                float acc = 0.0f;
                #pragma unroll 16
                for (int i = 0; i < 256; ++i)
                    acc += lds_x[c0 + i] * pW[(size_t)i * TK];
                lds_part[sub][g] = acc;
            }
        }
        __syncthreads();
        if (t < TK) {
            const float dot = lds_part[0][t] + lds_part[1][t]
                            + lds_part[2][t] + lds_part[3][t];
            const float p = __expf(dot + bias[t]);
            float v = p;
            if (t >= 2 * K) {
                const int k = t - 2 * K;
                v = kappa_old[(size_t)b * K + k] + p;
                out[OUT_KAPPA + (size_t)b * K + k] = v;
            }
            lds_abk[t] = v;
        }
        __syncthreads();

        // ---- row 0 only: 4th prefetch quad (row 1's comes via cross-row refill) ----
        if (r == 0) {
            D0 = NTLOAD(oh + t + 3072);  D1 = NTLOAD(oh + t + 3328);
            D2 = NTLOAD(oh + t + 3584);  D3 = NTLOAD(oh + t + 3840);
        }

        // ---- phi[l] = scale * sum_k alpha_k * exp(-beta_k*(kappa_k-l)^2) ----
        {
            float s[8];
            #pragma unroll
            for (int j = 0; j < 8; ++j) s[j] = 0.0f;
            #pragma unroll
            for (int k = 0; k < K; ++k) {
                const float a  = lds_abk[k];
                const float be = lds_abk[K + k];
                const float kp = lds_abk[2 * K + k];
                #pragma unroll
                for (int j = 0; j < 8; ++j) {
                    const float d = kp - (float)(t + (j << 8));
                    s[j] += a * __expf(-be * d * d);
                }
            }
            const float scale = 2048.0f / (float)text_lens[b];
            float* out_phi = out + OUT_PHI + (size_t)b * (L + 1);
            #pragma unroll
            for (int j = 0; j < 8; ++j) {
                const int l = t + (j << 8);
                const float v = s[j] * scale;
                lds_phi[l] = v;
                out_phi[l] = v;
            }
            if (t == 0) {  // tail l = 2048 (output only)
                float sv = 0.0f;
                #pragma unroll
                for (int k = 0; k < K; ++k) {
                    const float d = lds_abk[2 * K + k] - 2048.0f;
                    sv += lds_abk[k] * __expf(-lds_abk[K + k] * d * d);
                }
                out_phi[L] = sv * scale;
            }
        }
        __syncthreads();

        // ---- stream this row; refills cross into the next row for r==0 ----
        {
            const int rbase = r * 40960;   // row offset in 16B chunks

            #define PROC(vv, ii) {                                          \
                const float s_ = vv.x + vv.y + vv.z + vv.w;                 \
                if (s_ != 0.0f) {                                           \
                    const int i_ = (ii);                                    \
                    const int l_ = i_ / 20;                                 \
                    const int v0 = (i_ - l_ * 20) * 4;                      \
                    const int jo = (int)(vv.y + 2.0f * vv.z + 3.0f * vv.w); \
                    atomicAdd(&lds_w[v0 + jo], lds_phi[l_]);                \
                } }
            #define REFILL(Q, base) {                                       \
                Q##0 = NTLOAD(oh + (base));       Q##1 = NTLOAD(oh + (base) + 256); \
                Q##2 = NTLOAD(oh + (base) + 512); Q##3 = NTLOAD(oh + (base) + 768); }

            #pragma unroll 1
            for (int q = 0; q < 40; q += 4) {
                const int ia = t + (q << 10);              // row-relative
                PROC(A0, ia);       PROC(A1, ia + 256);
                PROC(A2, ia + 512); PROC(A3, ia + 768);
                if (r == 0 || q + 4 < 40) REFILL(A, rbase + t + ((q + 4) << 10));
                const int ib = ia + 1024;
                PROC(B0, ib);       PROC(B1, ib + 256);
                PROC(B2, ib + 512); PROC(B3, ib + 768);
                if (r == 0 || q + 5 < 40) REFILL(B, rbase + t + ((q + 5) << 10));
                const int ic = ia + 2048;
                PROC(C0, ic);       PROC(C1, ic + 256);
                PROC(C2, ic + 512); PROC(C3, ic + 768);
                if (r == 0 || q + 6 < 40) REFILL(C, rbase + t + ((q + 6) << 10));
                const int id = ia + 3072;
                PROC(D0, id);       PROC(D1, id + 256);
                PROC(D2, id + 512); PROC(D3, id + 768);
                if (r == 0 || q + 7 < 40) REFILL(D, rbase + t + ((q + 7) << 10));
            }
            #undef REFILL
            #undef PROC
        }
        __syncthreads();

        if (t < V) out[(size_t)b * V + t] = lds_w[t];
        // next iteration's lds_x store + barrier orders lds_w re-zero safely
    }
}

extern "C" void kernel_launch(void* const* d_in, const int* in_sizes, int n_in,
                              void* d_out, int out_size, void* d_ws, size_t ws_size,
                              hipStream_t stream) {
    const float* x         = (const float*)d_in[0];
    const float* W         = (const float*)d_in[1];
    const float* bias      = (const float*)d_in[2];
    const float* kappa_old = (const float*)d_in[3];
    const float* onehots   = (const float*)d_in[4];
    const int*   text_lens = (const int*)d_in[5];
    float* out = (float*)d_out;

    window_fused_kernel<<<B / 2, 256, 0, stream>>>(x, W, bias, kappa_old,
                                                   onehots, text_lens, out);
}